// Round 8
// baseline (335.095 us; speedup 1.0000x reference)
//
#include <hip/hip_runtime.h>
#include <hip/hip_bf16.h>
#include <math.h>

constexpr int B = 64, S = 1024, H = 1024;

typedef __attribute__((ext_vector_type(8))) short bf16x8;
typedef __attribute__((ext_vector_type(4))) float f32x4;

__device__ __forceinline__ unsigned pkbf2(float x, float y) {
    union { __hip_bfloat162 h; unsigned u; } r;
    r.h = __float22bfloat162_rn(float2{x, y});   // v_cvt_pk_bf16_f32 (RNE)
    return r.u;
}
__device__ __forceinline__ bf16x8 pack8(float4 a, float4 b) {
    union { unsigned u[4]; bf16x8 v; } r;
    r.u[0] = pkbf2(a.x, a.y);
    r.u[1] = pkbf2(a.z, a.w);
    r.u[2] = pkbf2(b.x, b.y);
    r.u[3] = pkbf2(b.z, b.w);
    return r.v;
}

__device__ __forceinline__ float tanh_fast(float x) {
    return 1.0f - 2.0f / (__expf(2.0f * x) + 1.0f);
}

// ---------------------------------------------------------------------------
// Kernel 1: hb[b][o] = attn_b[o] + sum_h hidden[b,h] * attn_W[o,h]   (f32)
// ---------------------------------------------------------------------------
__global__ __launch_bounds__(256) void k_hproj(const float* __restrict__ hidden,
                                               const float* __restrict__ attn_W,
                                               const float* __restrict__ attn_b,
                                               float* __restrict__ hb) {
    int wid  = blockIdx.x * 4 + (threadIdx.x >> 6);
    int lane = threadIdx.x & 63;
    int b = wid >> 10;
    int o = wid & 1023;
    const float* hrow = hidden + (size_t)b * H;
    const float* wrow = attn_W + (size_t)o * (2 * H);
    float acc = 0.f;
#pragma unroll
    for (int k = 0; k < 4; ++k) {
        int idx = lane * 4 + k * 256;
        float4 hv = *(const float4*)(hrow + idx);
        float4 wv = *(const float4*)(wrow + idx);
        acc += hv.x * wv.x + hv.y * wv.y + hv.z * wv.z + hv.w * wv.w;
    }
#pragma unroll
    for (int off = 32; off > 0; off >>= 1) acc += __shfl_down(acc, off, 64);
    if (lane == 0) hb[(size_t)b * H + o] = acc + attn_b[o];
}

// ---------------------------------------------------------------------------
// Kernel 2: We = attn_W[:, H:] -> bf16, packed in MFMA B-fragment order.
// Fragment (ot, kb): 16 o-cols x 32 k; lane = t16 + 16*q reads o=ot*16+t16,
// k = kb*32 + q*8 .. +7.  Element offset = ((ot*32 + kb)*64 + lane)*8.
// A wave's frag load is then one coalesced 1KB global_load_dwordx4.
// ---------------------------------------------------------------------------
__global__ __launch_bounds__(256) void k_convW(const float* __restrict__ attn_W,
                                               short* __restrict__ WeB2) {
    int gid = blockIdx.x * 256 + threadIdx.x;   // 131072 granules
    int lane = gid & 63;
    int kb   = (gid >> 6) & 31;
    int ot   = gid >> 11;
    int o  = ot * 16 + (lane & 15);
    int k0 = kb * 32 + (lane >> 4) * 8;
    const float* src = attn_W + (size_t)o * (2 * H) + H + k0;
    float4 a = *(const float4*)src;
    float4 c = *(const float4*)(src + 4);
    *(bf16x8*)(WeB2 + (size_t)gid * 8) = pack8(a, c);
}

// ---------------------------------------------------------------------------
// Kernel 3: MFMA energy GEMM + tanh + v_W-dot epilogue.
// 1D grid 4096; nbq=(L>>3)&3, Mtile=(L&7)|((L>>5)<<3)  ->  the 4 nbq partners
// of one Mtile share L%8 (same XCD round-robin slot) so the enc A-panel is
// L2-shared, and they're temporally adjacent.
// 256 thr = 4 waves, wave tile 64x64. A (enc f32) reg-staged -> cvt_pk bf16 ->
// XOR-swizzled LDS dbuf (16 KB total). B frags straight from L2 (coalesced,
// fragment-ordered WeB2), register double-buffered one K-step ahead.
// ---------------------------------------------------------------------------
struct BF { bf16x8 f[2][4]; };

__device__ __forceinline__ BF loadB(const short* __restrict__ bbase, int ks) {
    BF r;
#pragma unroll
    for (int kh = 0; kh < 2; ++kh)
#pragma unroll
        for (int nf = 0; nf < 4; ++nf)
            r.f[kh][nf] = *(const bf16x8*)(bbase + nf * 16384 + ks * 1024 + kh * 512);
    return r;
}

__global__ __launch_bounds__(256, 3) void k_mfma(const float* __restrict__ enc,
                                                 const short* __restrict__ WeB2,
                                                 const float* __restrict__ v_W,
                                                 const float* __restrict__ hb,
                                                 float* __restrict__ pscore) {
    __shared__ short Abuf[2][64 * 64];    // 16 KB total

    const int tid  = threadIdx.x;
    const int lane = tid & 63;
    const int wv   = tid >> 6;        // 0..3
    const int t16  = lane & 15;
    const int q    = lane >> 4;

    const int L     = blockIdx.x;
    const int nbq   = (L >> 3) & 3;
    const int Mtile = (L & 7) | ((L >> 5) << 3);
    const int b  = Mtile >> 4;
    const int s0 = (Mtile & 15) * 64;

    // A staging roles: 4 threads per row, 16 consecutive floats (2 granules)
    const int am = tid >> 2;          // row 0..63
    const int g0 = (tid & 3) * 2;     // granule 0,2,4,6
    const float* abase = enc + ((size_t)(s0 + am) * B + b) * H + g0 * 8;
    const int s7  = am & 7;
    const int ap0 = (g0 ^ s7) * 8;
    const int ap1 = ((g0 + 1) ^ s7) * 8;

    // B fragment base: ot = otb + nf, kb = ks*2 + kh
    const int otb = nbq * 16 + wv * 4;
    const short* bbase = WeB2 + ((size_t)otb * 32 * 64 + lane) * 8;

    f32x4 acc[4][4];
#pragma unroll
    for (int mf = 0; mf < 4; ++mf)
#pragma unroll
        for (int nf = 0; nf < 4; ++nf) acc[mf][nf] = (f32x4){0.f, 0.f, 0.f, 0.f};

    const int swz = t16 & 7;
    const int nwv = wv * 64;

    // ---- prologue: A step 0 -> LDS buf0; B step 0 -> regs
    {
        float4 v0 = *(const float4*)(abase);
        float4 v1 = *(const float4*)(abase + 4);
        float4 v2 = *(const float4*)(abase + 8);
        float4 v3 = *(const float4*)(abase + 12);
        *(bf16x8*)&Abuf[0][am * 64 + ap0] = pack8(v0, v1);
        *(bf16x8*)&Abuf[0][am * 64 + ap1] = pack8(v2, v3);
    }
    BF bc = loadB(bbase, 0);
    __syncthreads();

    // ---- main K loop: 16 steps of BK=64
#pragma unroll 2
    for (int ks = 0; ks < 16; ++ks) {
        const int cur = ks & 1;
        const int nxt = cur ^ 1;
        const bool pf = (ks < 15);
        BF bn;
        float4 v0, v1, v2, v3;
        if (pf) {
            bn = loadB(bbase, ks + 1);               // B prefetch (regs)
            const float* asrc = abase + (ks + 1) * 64;
            v0 = *(const float4*)(asrc);
            v1 = *(const float4*)(asrc + 4);
            v2 = *(const float4*)(asrc + 8);
            v3 = *(const float4*)(asrc + 12);
        }

        const short* Ab = &Abuf[cur][0];
#pragma unroll
        for (int kh = 0; kh < 2; ++kh) {
            const int gq = kh * 4 + q;
            const int gp = (gq ^ swz) * 8;
            bf16x8 af[4];
#pragma unroll
            for (int mf = 0; mf < 4; ++mf)
                af[mf] = *(const bf16x8*)(Ab + (mf * 16 + t16) * 64 + gp);
#pragma unroll
            for (int mf = 0; mf < 4; ++mf)
#pragma unroll
                for (int nf = 0; nf < 4; ++nf)
                    acc[mf][nf] = __builtin_amdgcn_mfma_f32_16x16x32_bf16(
                        af[mf], bc.f[kh][nf], acc[mf][nf], 0, 0, 0);
        }

        if (pf) {
            *(bf16x8*)&Abuf[nxt][am * 64 + ap0] = pack8(v0, v1);
            *(bf16x8*)&Abuf[nxt][am * 64 + ap1] = pack8(v2, v3);
        }
        __syncthreads();
        bc = bn;
    }

    // ---- epilogue: tanh + v_W dot over this block's 256 o-cols
    float psum[4][4];
#pragma unroll
    for (int mf = 0; mf < 4; ++mf)
#pragma unroll
        for (int r = 0; r < 4; ++r) psum[mf][r] = 0.f;

#pragma unroll
    for (int nf = 0; nf < 4; ++nf) {
        const int o = nbq * 256 + nwv + nf * 16 + t16;
        const float hbv = hb[(size_t)b * H + o];
        const float vw  = v_W[o];
#pragma unroll
        for (int mf = 0; mf < 4; ++mf)
#pragma unroll
            for (int r = 0; r < 4; ++r)
                psum[mf][r] += vw * tanh_fast(acc[mf][nf][r] + hbv);
    }
#pragma unroll
    for (int mf = 0; mf < 4; ++mf)
#pragma unroll
        for (int r = 0; r < 4; ++r) {
#pragma unroll
            for (int off = 1; off < 16; off <<= 1)
                psum[mf][r] += __shfl_xor(psum[mf][r], off, 64);
        }

    float* red = (float*)&Abuf[0][0];   // dead LDS as scratch (1 KB)
    if (t16 == 0) {
#pragma unroll
        for (int mf = 0; mf < 4; ++mf)
#pragma unroll
            for (int r = 0; r < 4; ++r)
                red[(mf * 16 + q * 4 + r) * 4 + wv] = psum[mf][r];
    }
    __syncthreads();
    if (tid < 64) {
        float s = red[tid * 4 + 0] + red[tid * 4 + 1] + red[tid * 4 + 2] + red[tid * 4 + 3];
        pscore[(size_t)nbq * (B * S) + (size_t)Mtile * 64 + tid] = s;
    }
}

// ---------------------------------------------------------------------------
// Kernel 4: combine 4 partials + mask + softmax over S. One block per b.
// ---------------------------------------------------------------------------
__global__ __launch_bounds__(256) void k_softmax(const float* __restrict__ pscore,
                                                 const int* __restrict__ mask,
                                                 float* __restrict__ out) {
    const int b = blockIdx.x;
    const int tid = threadIdx.x;
    __shared__ float sm[64];
    float v[4];
    float mx = -INFINITY;
#pragma unroll
    for (int k = 0; k < 4; ++k) {
        const int s = tid + k * 256;
        const size_t idx = (size_t)b * S + s;
        float sc = pscore[idx] + pscore[(size_t)(B * S) + idx]
                 + pscore[2 * (size_t)(B * S) + idx] + pscore[3 * (size_t)(B * S) + idx];
        sc = (mask[idx] == 0) ? -1e10f : sc;
        v[k] = sc;
        mx = fmaxf(mx, sc);
    }
#pragma unroll
    for (int off = 32; off > 0; off >>= 1) mx = fmaxf(mx, __shfl_down(mx, off, 64));
    if ((tid & 63) == 0) sm[tid >> 6] = mx;
    __syncthreads();
    if (tid == 0) {
        float m = sm[0];
        for (int k = 1; k < 4; ++k) m = fmaxf(m, sm[k]);
        sm[4] = m;
    }
    __syncthreads();
    mx = sm[4];
    float sum = 0.f;
#pragma unroll
    for (int k = 0; k < 4; ++k) { v[k] = __expf(v[k] - mx); sum += v[k]; }
#pragma unroll
    for (int off = 32; off > 0; off >>= 1) sum += __shfl_down(sum, off, 64);
    if ((tid & 63) == 0) sm[8 + (tid >> 6)] = sum;
    __syncthreads();
    if (tid == 0) sm[12] = sm[8] + sm[9] + sm[10] + sm[11];
    __syncthreads();
    const float inv = 1.f / sm[12];
#pragma unroll
    for (int k = 0; k < 4; ++k) out[(size_t)b * S + tid + k * 256] = v[k] * inv;
}

// ---------------------------------------------------------------------------
extern "C" void kernel_launch(void* const* d_in, const int* in_sizes, int n_in,
                              void* d_out, int out_size, void* d_ws, size_t ws_size,
                              hipStream_t stream) {
    const float* hidden = (const float*)d_in[0];   // (B,H)
    const float* enc    = (const float*)d_in[1];   // (S,B,H)
    const int*   mask   = (const int*)d_in[2];     // (B,S)
    const float* attn_W = (const float*)d_in[3];   // (H,2H)
    const float* attn_b = (const float*)d_in[4];   // (H,)
    const float* v_W    = (const float*)d_in[5];   // (H,)
    float* out = (float*)d_out;                    // (B,S)

    float* hb     = (float*)d_ws;                          // 64K f32   (256 KB)
    short* WeB2   = (short*)(hb + (size_t)B * H);          // 1M bf16   (2 MB)
    float* pscore = (float*)(WeB2 + (size_t)H * H);        // 256K f32  (1 MB)

    k_hproj<<<dim3((B * H) / 4), 256, 0, stream>>>(hidden, attn_W, attn_b, hb);
    k_convW<<<dim3(512), 256, 0, stream>>>(attn_W, WeB2);
    k_mfma<<<dim3(4096), 256, 0, stream>>>(enc, WeB2, v_W, hb, pscore);
    k_softmax<<<dim3(B), 256, 0, stream>>>(pscore, mask, out);
}

// Round 10
// 250.336 us; speedup vs baseline: 1.3386x; 1.3386x over previous
//
#include <hip/hip_runtime.h>
#include <hip/hip_bf16.h>
#include <math.h>

constexpr int B = 64, S = 1024, H = 1024;

typedef __attribute__((ext_vector_type(8))) short bf16x8;
typedef __attribute__((ext_vector_type(4))) float f32x4;

__device__ __forceinline__ unsigned pkbf2(float x, float y) {
    union { __hip_bfloat162 h; unsigned u; } r;
    r.h = __float22bfloat162_rn(float2{x, y});   // v_cvt_pk_bf16_f32 (RNE)
    return r.u;
}
__device__ __forceinline__ bf16x8 pack8(float4 a, float4 b) {
    union { unsigned u[4]; bf16x8 v; } r;
    r.u[0] = pkbf2(a.x, a.y);
    r.u[1] = pkbf2(a.z, a.w);
    r.u[2] = pkbf2(b.x, b.y);
    r.u[3] = pkbf2(b.z, b.w);
    return r.v;
}

__device__ __forceinline__ float tanh_fast(float x) {
    return 1.0f - 2.0f / (__expf(2.0f * x) + 1.0f);
}

// ---------------------------------------------------------------------------
// Kernel 1: hb[b][o] = attn_b[o] + sum_h hidden[b,h] * attn_W[o,h]   (f32)
// ---------------------------------------------------------------------------
__global__ __launch_bounds__(256) void k_hproj(const float* __restrict__ hidden,
                                               const float* __restrict__ attn_W,
                                               const float* __restrict__ attn_b,
                                               float* __restrict__ hb) {
    int wid  = blockIdx.x * 4 + (threadIdx.x >> 6);
    int lane = threadIdx.x & 63;
    int b = wid >> 10;
    int o = wid & 1023;
    const float* hrow = hidden + (size_t)b * H;
    const float* wrow = attn_W + (size_t)o * (2 * H);
    float acc = 0.f;
#pragma unroll
    for (int k = 0; k < 4; ++k) {
        int idx = lane * 4 + k * 256;
        float4 hv = *(const float4*)(hrow + idx);
        float4 wv = *(const float4*)(wrow + idx);
        acc += hv.x * wv.x + hv.y * wv.y + hv.z * wv.z + hv.w * wv.w;
    }
#pragma unroll
    for (int off = 32; off > 0; off >>= 1) acc += __shfl_down(acc, off, 64);
    if (lane == 0) hb[(size_t)b * H + o] = acc + attn_b[o];
}

// ---------------------------------------------------------------------------
// Kernel 2: We = attn_W[:, H:] -> bf16, packed in MFMA B-fragment order.
// Fragment (ot, kb): lane = t16 + 16*q holds o=ot*16+t16, k=kb*32+q*8..+7.
// Element offset = ((ot*32 + kb)*64 + lane)*8.
// ---------------------------------------------------------------------------
__global__ __launch_bounds__(256) void k_convW(const float* __restrict__ attn_W,
                                               short* __restrict__ WeB2) {
    int gid = blockIdx.x * 256 + threadIdx.x;   // 131072 granules
    int lane = gid & 63;
    int kb   = (gid >> 6) & 31;
    int ot   = gid >> 11;
    int o  = ot * 16 + (lane & 15);
    int k0 = kb * 32 + (lane >> 4) * 8;
    const float* src = attn_W + (size_t)o * (2 * H) + H + k0;
    float4 a = *(const float4*)src;
    float4 c = *(const float4*)(src + 4);
    *(bf16x8*)(WeB2 + (size_t)gid * 8) = pack8(a, c);
}

// ---------------------------------------------------------------------------
// Kernel 3: MFMA energy GEMM + tanh + v_W-dot epilogue.
// 1D grid 4096; nbq=(L>>3)&3, Mtile=(L&7)|((L>>5)<<3): the 4 nbq partners of
// one Mtile share L%8 (same XCD) -> enc A-panel L2-shared (verified r8:
// FETCH 545->237 MB).
// 256 thr = 4 waves, wave tile 64x64. A (enc f32) reg-staged -> cvt_pk bf16 ->
// XOR-swizzled LDS dbuf (16 KB only). B frags loaded AT USE from L2
// (fragment-ordered WeB2, coalesced 1KB/wave loads) -- no carried prefetch
// struct, no unroll-2: kills the r8 scratch spill (WRITE_SIZE 307MB).
// ---------------------------------------------------------------------------
__global__ __launch_bounds__(256, 2) void k_mfma(const float* __restrict__ enc,
                                                 const short* __restrict__ WeB2,
                                                 const float* __restrict__ v_W,
                                                 const float* __restrict__ hb,
                                                 float* __restrict__ pscore) {
    __shared__ short Abuf[2][64 * 64];    // 16 KB total

    const int tid  = threadIdx.x;
    const int lane = tid & 63;
    const int wv   = tid >> 6;        // 0..3
    const int t16  = lane & 15;
    const int q    = lane >> 4;

    const int L     = blockIdx.x;
    const int nbq   = (L >> 3) & 3;
    const int Mtile = (L & 7) | ((L >> 5) << 3);
    const int b  = Mtile >> 4;
    const int s0 = (Mtile & 15) * 64;

    // A staging roles: 4 threads per row, 16 consecutive floats (2 granules)
    const int am = tid >> 2;          // row 0..63
    const int g0 = (tid & 3) * 2;     // granule 0,2,4,6
    const float* abase = enc + ((size_t)(s0 + am) * B + b) * H + g0 * 8;
    const int s7  = am & 7;
    const int ap0 = (g0 ^ s7) * 8;
    const int ap1 = ((g0 + 1) ^ s7) * 8;

    // B fragment base: ot = otb + nf, kb = ks*2 + kh
    const int otb = nbq * 16 + wv * 4;
    const short* bbase = WeB2 + ((size_t)otb * 32 * 64 + lane) * 8;

    f32x4 acc[4][4];
#pragma unroll
    for (int mf = 0; mf < 4; ++mf)
#pragma unroll
        for (int nf = 0; nf < 4; ++nf) acc[mf][nf] = (f32x4){0.f, 0.f, 0.f, 0.f};

    const int swz = t16 & 7;
    const int nwv = wv * 64;

    // ---- prologue: A step 0 -> LDS buf0
    {
        float4 v0 = *(const float4*)(abase);
        float4 v1 = *(const float4*)(abase + 4);
        float4 v2 = *(const float4*)(abase + 8);
        float4 v3 = *(const float4*)(abase + 12);
        *(bf16x8*)&Abuf[0][am * 64 + ap0] = pack8(v0, v1);
        *(bf16x8*)&Abuf[0][am * 64 + ap1] = pack8(v2, v3);
    }
    __syncthreads();

    // ---- main K loop: 16 steps of BK=64
    const short* bptr = bbase;                   // advances 1024 shorts/step
    for (int ks = 0; ks < 16; ++ks) {
        const int cur = ks & 1;
        const int nxt = cur ^ 1;
        const bool pf = (ks < 15);
        float4 v0, v1, v2, v3;
        if (pf) {
            const float* asrc = abase + (ks + 1) * 64;   // A prefetch (regs)
            v0 = *(const float4*)(asrc);
            v1 = *(const float4*)(asrc + 4);
            v2 = *(const float4*)(asrc + 8);
            v3 = *(const float4*)(asrc + 12);
        }

        const short* Ab = &Abuf[cur][0];
#pragma unroll
        for (int kh = 0; kh < 2; ++kh) {
            bf16x8 bfr[4];
#pragma unroll
            for (int nf = 0; nf < 4; ++nf)               // B at use, from L2
                bfr[nf] = *(const bf16x8*)(bptr + nf * 16384 + kh * 512);
            const int gq = kh * 4 + q;
            const int gp = (gq ^ swz) * 8;
            bf16x8 af[4];
#pragma unroll
            for (int mf = 0; mf < 4; ++mf)
                af[mf] = *(const bf16x8*)(Ab + (mf * 16 + t16) * 64 + gp);
#pragma unroll
            for (int mf = 0; mf < 4; ++mf)
#pragma unroll
                for (int nf = 0; nf < 4; ++nf)
                    acc[mf][nf] = __builtin_amdgcn_mfma_f32_16x16x32_bf16(
                        af[mf], bfr[nf], acc[mf][nf], 0, 0, 0);
        }
        bptr += 1024;

        if (pf) {
            *(bf16x8*)&Abuf[nxt][am * 64 + ap0] = pack8(v0, v1);
            *(bf16x8*)&Abuf[nxt][am * 64 + ap1] = pack8(v2, v3);
        }
        __syncthreads();
    }

    // ---- epilogue: tanh + v_W dot over this block's 256 o-cols
    float psum[4][4];
#pragma unroll
    for (int mf = 0; mf < 4; ++mf)
#pragma unroll
        for (int r = 0; r < 4; ++r) psum[mf][r] = 0.f;

#pragma unroll
    for (int nf = 0; nf < 4; ++nf) {
        const int o = nbq * 256 + nwv + nf * 16 + t16;
        const float hbv = hb[(size_t)b * H + o];
        const float vw  = v_W[o];
#pragma unroll
        for (int mf = 0; mf < 4; ++mf)
#pragma unroll
            for (int r = 0; r < 4; ++r)
                psum[mf][r] += vw * tanh_fast(acc[mf][nf][r] + hbv);
    }
#pragma unroll
    for (int mf = 0; mf < 4; ++mf)
#pragma unroll
        for (int r = 0; r < 4; ++r) {
#pragma unroll
            for (int off = 1; off < 16; off <<= 1)
                psum[mf][r] += __shfl_xor(psum[mf][r], off, 64);
        }

    float* red = (float*)&Abuf[0][0];   // dead LDS as scratch (1 KB)
    if (t16 == 0) {
#pragma unroll
        for (int mf = 0; mf < 4; ++mf)
#pragma unroll
            for (int r = 0; r < 4; ++r)
                red[(mf * 16 + q * 4 + r) * 4 + wv] = psum[mf][r];
    }
    __syncthreads();
    if (tid < 64) {
        float s = red[tid * 4 + 0] + red[tid * 4 + 1] + red[tid * 4 + 2] + red[tid * 4 + 3];
        pscore[(size_t)nbq * (B * S) + (size_t)Mtile * 64 + tid] = s;
    }
}

// ---------------------------------------------------------------------------
// Kernel 4: combine 4 partials + mask + softmax over S. One block per b.
// ---------------------------------------------------------------------------
__global__ __launch_bounds__(256) void k_softmax(const float* __restrict__ pscore,
                                                 const int* __restrict__ mask,
                                                 float* __restrict__ out) {
    const int b = blockIdx.x;
    const int tid = threadIdx.x;
    __shared__ float sm[64];
    float v[4];
    float mx = -INFINITY;
#pragma unroll
    for (int k = 0; k < 4; ++k) {
        const int s = tid + k * 256;
        const size_t idx = (size_t)b * S + s;
        float sc = pscore[idx] + pscore[(size_t)(B * S) + idx]
                 + pscore[2 * (size_t)(B * S) + idx] + pscore[3 * (size_t)(B * S) + idx];
        sc = (mask[idx] == 0) ? -1e10f : sc;
        v[k] = sc;
        mx = fmaxf(mx, sc);
    }
#pragma unroll
    for (int off = 32; off > 0; off >>= 1) mx = fmaxf(mx, __shfl_down(mx, off, 64));
    if ((tid & 63) == 0) sm[tid >> 6] = mx;
    __syncthreads();
    if (tid == 0) {
        float m = sm[0];
        for (int k = 1; k < 4; ++k) m = fmaxf(m, sm[k]);
        sm[4] = m;
    }
    __syncthreads();
    mx = sm[4];
    float sum = 0.f;
#pragma unroll
    for (int k = 0; k < 4; ++k) { v[k] = __expf(v[k] - mx); sum += v[k]; }
#pragma unroll
    for (int off = 32; off > 0; off >>= 1) sum += __shfl_down(sum, off, 64);
    if ((tid & 63) == 0) sm[8 + (tid >> 6)] = sum;
    __syncthreads();
    if (tid == 0) sm[12] = sm[8] + sm[9] + sm[10] + sm[11];
    __syncthreads();
    const float inv = 1.f / sm[12];
#pragma unroll
    for (int k = 0; k < 4; ++k) out[(size_t)b * S + tid + k * 256] = v[k] * inv;
}

// ---------------------------------------------------------------------------
extern "C" void kernel_launch(void* const* d_in, const int* in_sizes, int n_in,
                              void* d_out, int out_size, void* d_ws, size_t ws_size,
                              hipStream_t stream) {
    const float* hidden = (const float*)d_in[0];   // (B,H)
    const float* enc    = (const float*)d_in[1];   // (S,B,H)
    const int*   mask   = (const int*)d_in[2];     // (B,S)
    const float* attn_W = (const float*)d_in[3];   // (H,2H)
    const float* attn_b = (const float*)d_in[4];   // (H,)
    const float* v_W    = (const float*)d_in[5];   // (H,)
    float* out = (float*)d_out;                    // (B,S)

    float* hb     = (float*)d_ws;                          // 64K f32   (256 KB)
    short* WeB2   = (short*)(hb + (size_t)B * H);          // 1M bf16   (2 MB)
    float* pscore = (float*)(WeB2 + (size_t)H * H);        // 256K f32  (1 MB)

    k_hproj<<<dim3((B * H) / 4), 256, 0, stream>>>(hidden, attn_W, attn_b, hb);
    k_convW<<<dim3(512), 256, 0, stream>>>(attn_W, WeB2);
    k_mfma<<<dim3(4096), 256, 0, stream>>>(enc, WeB2, v_W, hb, pscore);
    k_softmax<<<dim3(B), 256, 0, stream>>>(pscore, mask, out);
}